// Round 9
// baseline (1485.472 us; speedup 1.0000x reference)
//
#include <hip/hip_runtime.h>
#include <hip/hip_bf16.h>
#include <hip/hip_fp16.h>
#include <stdint.h>

#define T_STEPS 256
#define BATCH 512

typedef _Float16 f16x8 __attribute__((ext_vector_type(8)));
typedef _Float16 h2_t  __attribute__((ext_vector_type(2)));
typedef float    f32x4 __attribute__((ext_vector_type(4)));

__device__ __forceinline__ float fdot2(uint32_t w, uint32_t c, float acc) {
#if __has_builtin(__builtin_amdgcn_fdot2)
    h2_t a, b;
    __builtin_memcpy(&a, &w, 4);
    __builtin_memcpy(&b, &c, 4);
    return __builtin_amdgcn_fdot2(a, b, acc, false);
#else
    union { uint32_t u; _Float16 h[2]; } A, B;
    A.u = w; B.u = c;
    return acc + (float)A.h[0]*(float)B.h[0] + (float)A.h[1]*(float)B.h[1];
#endif
}

__device__ __forceinline__ float sigmoidf_(float x) {
    return 1.f / (1.f + __expf(-x));
}
__device__ __forceinline__ float tanhf_(float x) {
    float ax = fabsf(x);
    float e = __expf(-2.f * ax);
    float r = (1.f - e) / (1.f + e);
    return copysignf(r, x);
}

// ---------------- prep: concat QCNN weights ----------------
__global__ void concat_qw(const float* __restrict__ fm_w, const float* __restrict__ fm_b,
                          const float* __restrict__ c1_w, const float* __restrict__ c1_b,
                          const float* __restrict__ p1_w, const float* __restrict__ p1_b,
                          const float* __restrict__ c2_w, const float* __restrict__ c2_b,
                          const float* __restrict__ p2_w, const float* __restrict__ p2_b,
                          const float* __restrict__ c3_w, const float* __restrict__ c3_b,
                          float* __restrict__ qw) {
    for (int k = threadIdx.x; k < 780; k += 256) {
        float v;
        if      (k < 128) v = fm_w[k];
        else if (k < 144) v = fm_b[k-128];
        else if (k < 400) v = c1_w[k-144];
        else if (k < 416) v = c1_b[k-400];
        else if (k < 608) v = p1_w[k-416];
        else if (k < 620) v = p1_b[k-608];
        else if (k < 716) v = c2_w[k-620];
        else if (k < 724) v = c2_b[k-716];
        else if (k < 756) v = p2_w[k-724];
        else if (k < 760) v = p2_b[k-756];
        else if (k < 776) v = c3_w[k-760];
        else              v = c3_b[k-776];
        qw[k] = v;
    }
}

// ---------------- prep: B-fragments (f16), global-tile layout ----------------
// bfragsG[((n*8+q)*64+l)]: N-tile n (col = n*16 + (l&15), col = gate*256 + j),
// K-tile q (k = q*32 + (l>>4)*8 + e). k-order errors cancel (A same mapping).
__global__ void pack_bfrag(const float* __restrict__ f_w, const float* __restrict__ i_w,
                           const float* __restrict__ u_w, const float* __restrict__ o_w,
                           uint4* __restrict__ bfragsG) {
    int idx = blockIdx.x * 256 + threadIdx.x;      // 0..32767
    int l = idx & 63, q = (idx >> 6) & 7, n = idx >> 9;
    int col = n * 16 + (l & 15);
    int g = col >> 8, j = col & 255;
    const float* W = (g == 0) ? f_w : (g == 1) ? i_w : (g == 2) ? u_w : o_w;
    union { uint4 u; _Float16 h[8]; } P;
#pragma unroll
    for (int e = 0; e < 8; ++e) {
        int k = q * 32 + ((l >> 4) * 8) + e;       // 0..255 (h part only)
        P.h[e] = (_Float16)W[j * 260 + 4 + k];
    }
    bfragsG[idx] = P.u;
}

// ---------------- prep: x-part weights xwG[g][k][j] f16 ----------------
__global__ void pack_xw(const float* __restrict__ f_w, const float* __restrict__ i_w,
                        const float* __restrict__ u_w, const float* __restrict__ o_w,
                        _Float16* __restrict__ xwG) {
    int t = blockIdx.x * 256 + threadIdx.x;        // 0..4095
    int g = t >> 10, k = (t >> 8) & 3, j = t & 255;
    const float* W = (g == 0) ? f_w : (g == 1) ? i_w : (g == 2) ? u_w : o_w;
    xwG[t] = (_Float16)W[j * 260 + k];
}

// ---------------- QCNN feature extractor ----------------
__global__ void qcnn_kernel(const float* __restrict__ in, const float* __restrict__ qw,
                            _Float16* __restrict__ feats) {
    int r = blockIdx.x * 256 + threadIdx.x;   // 0..131071
    const float* x = in + (size_t)r * 8;
    float v0[8];
#pragma unroll
    for (int i = 0; i < 8; ++i) v0[i] = x[i];
    float v1[16];
#pragma unroll
    for (int o = 0; o < 16; ++o) {
        float s = qw[128 + o];
#pragma unroll
        for (int i = 0; i < 8; ++i) s += qw[o*8 + i] * v0[i];
        v1[o] = tanhf_(s);
    }
    float v2[16];
#pragma unroll
    for (int o = 0; o < 16; ++o) {
        float s = qw[400 + o];
#pragma unroll
        for (int i = 0; i < 16; ++i) s += qw[144 + o*16 + i] * v1[i];
        v2[o] = tanhf_(s);
    }
    float v3[12];
#pragma unroll
    for (int o = 0; o < 12; ++o) {
        float s = qw[608 + o];
#pragma unroll
        for (int i = 0; i < 16; ++i) s += qw[416 + o*16 + i] * v2[i];
        v3[o] = tanhf_(s);
    }
    float v4[8];
#pragma unroll
    for (int o = 0; o < 8; ++o) {
        float s = qw[716 + o];
#pragma unroll
        for (int i = 0; i < 12; ++i) s += qw[620 + o*12 + i] * v3[i];
        v4[o] = tanhf_(s);
    }
    float v5[4];
#pragma unroll
    for (int o = 0; o < 4; ++o) {
        float s = qw[756 + o];
#pragma unroll
        for (int i = 0; i < 8; ++i) s += qw[724 + o*8 + i] * v4[i];
        v5[o] = tanhf_(s);
    }
    union { uint32_t u[2]; _Float16 h[4]; } P;
#pragma unroll
    for (int o = 0; o < 4; ++o) {
        float s = qw[776 + o];
#pragma unroll
        for (int i = 0; i < 4; ++i) s += qw[760 + o*4 + i] * v5[i];
        P.h[o] = (_Float16)tanhf_(s);
    }
    *reinterpret_cast<uint2*>(feats + (size_t)r * 4) = make_uint2(P.u[0], P.u[1]);
}

// ---------------- persistent LSTM: 64 blocks x 512 threads, 8 samples/block ----
// 8 waves = 2 waves/SIMD (co-scheduling hides VALU+LDS under the other wave's
// MFMA — m114). Per-SIMD MFMA = 2 x 64 x ~17cy = 2176 cy/step (the invariant
// floor at any block count; r8 proved cross-block sync costs 5.7us/step, so we
// stay block-local). Wave w owns j in [w*32,(w+1)*32): tiles n(m) =
// (m>>1)*16 + w*2 + (m&1), m = gate*2 + half -> all 4 gates of a j in-wave.
// B split: q0..2 register-resident (96 VGPR; AGPR demotion harmless — MFMA
// reads AGPR natively), q4,q5 in LDS (128 KB), q3,q6,q7 streamed from L2 each
// step (12 MB/step ~ 10 TB/s aggregate, L2-resident source).
// M=8 row-dup trick: A row = (l&15)&7 -> C rows 8..15 duplicate samples 0..7,
// so EVERY lane's C regs hold its epilogue operands (samples 4*sg+r, its own
// j) -> zero LDS/shfl redistribution; select C[2g+i_] via cndmask (never
// runtime-index the array — rule #20 scratch trap).
__global__ __launch_bounds__(512, 2)
void lstm_kernel(const uint4* __restrict__ bfragsG, const _Float16* __restrict__ xwG,
                 const _Float16* __restrict__ feats,
                 const float* __restrict__ f_b, const float* __restrict__ i_b,
                 const float* __restrict__ u_b, const float* __restrict__ o_b,
                 const float* __restrict__ head_w, const float* __restrict__ head_bp,
                 float* __restrict__ out) {
    __shared__ uint4     blds[2][64][64];               // 131072 B : B q=4,5
    __shared__ __align__(16) _Float16 comb[2][8][264];  //   8448 B : [buf][s][k] h
    __shared__ float     redL[2][8][2][4];              //    512 B : head partials

    const int tid = threadIdx.x;
    const int w   = tid >> 6;          // wave 0..7 -> j range [w*32, w*32+32)
    const int l   = tid & 63;
    const int i_  = l >> 5;            // tile half (j +0 / +16)
    const int sg  = (l >> 4) & 1;      // sample group (samples 4sg..4sg+3)
    const int jj  = l & 15;
    const int jloc = w * 32 + i_ * 16 + jj;   // this lane's output dim
    const int sbase = blockIdx.x * 8;

    int nIdx[8];
#pragma unroll
    for (int m = 0; m < 8; ++m) nIdx[m] = (m >> 1) * 16 + w * 2 + (m & 1);

    // ---- init LDS ----
    for (int idx = tid; idx < 8192; idx += 512) {
        int n = idx >> 7, qq = (idx >> 6) & 1, ll = idx & 63;
        blds[qq][n][ll] = bfragsG[(n * 8 + 4 + qq) * 64 + ll];
    }
    for (int idx = tid; idx < 2112; idx += 512)
        reinterpret_cast<uint32_t*>(&comb[0][0][0])[idx] = 0u;   // h_0 = 0 (both bufs)

    // ---- resident B: q = 0..2 ----
    f16x8 Br[8][3];
#pragma unroll
    for (int m = 0; m < 8; ++m)
#pragma unroll
        for (int q = 0; q < 3; ++q)
            Br[m][q] = *reinterpret_cast<const f16x8*>(bfragsG + (nIdx[m] * 8 + q) * 64 + l);

    // ---- per-lane epilogue constants ----
    float bias_[4] = { f_b[jloc], i_b[jloc], u_b[jloc], o_b[jloc] };
    uint32_t xwp0[4], xwp1[4];
#pragma unroll
    for (int g = 0; g < 4; ++g) {
        union { uint32_t u; _Float16 h[2]; } P;
        P.h[0] = xwG[g*1024 +       jloc]; P.h[1] = xwG[g*1024 + 256 + jloc];
        xwp0[g] = P.u;
        P.h[0] = xwG[g*1024 + 512 + jloc]; P.h[1] = xwG[g*1024 + 768 + jloc];
        xwp1[g] = P.u;
    }
    const float hwj = head_w[jloc];
    const float hb  = head_bp[0];

    __syncthreads();

    float cst[4] = {0.f, 0.f, 0.f, 0.f};    // c-state: samples 4sg+r at jloc

#pragma unroll 1
    for (int t = 0; t < T_STEPS; ++t) {
        const int cur = t & 1;

        // x_t for this lane's 4 samples (L2 broadcast loads)
        uint2 xr[4];
#pragma unroll
        for (int r = 0; r < 4; ++r)
            xr[r] = *reinterpret_cast<const uint2*>(
                feats + ((size_t)t * BATCH + sbase + 4 * sg + r) * 4);

        // stream q3 (consumed after 24 MFMAs -> L2 latency covered)
        f16x8 S3[8];
#pragma unroll
        for (int m = 0; m < 8; ++m)
            S3[m] = *reinterpret_cast<const f16x8*>(bfragsG + (nIdx[m] * 8 + 3) * 64 + l);

        const _Float16* ab = &comb[cur][(l & 15) & 7][(l >> 4) * 8];

        f32x4 C[8] = {{0.f,0.f,0.f,0.f},{0.f,0.f,0.f,0.f},{0.f,0.f,0.f,0.f},{0.f,0.f,0.f,0.f},
                      {0.f,0.f,0.f,0.f},{0.f,0.f,0.f,0.f},{0.f,0.f,0.f,0.f},{0.f,0.f,0.f,0.f}};

        // q0..q2: resident B
#pragma unroll
        for (int q = 0; q < 3; ++q) {
            f16x8 a = *reinterpret_cast<const f16x8*>(ab + q * 32);
#pragma unroll
            for (int m = 0; m < 8; ++m)
                C[m] = __builtin_amdgcn_mfma_f32_16x16x32_f16(a, Br[m][q], C[m], 0, 0, 0);
        }
        // stream q6 (consumed after 24 more MFMAs)
        f16x8 S6[8];
#pragma unroll
        for (int m = 0; m < 8; ++m)
            S6[m] = *reinterpret_cast<const f16x8*>(bfragsG + (nIdx[m] * 8 + 6) * 64 + l);
        // q3: streamed
        {
            f16x8 a = *reinterpret_cast<const f16x8*>(ab + 3 * 32);
#pragma unroll
            for (int m = 0; m < 8; ++m)
                C[m] = __builtin_amdgcn_mfma_f32_16x16x32_f16(a, S3[m], C[m], 0, 0, 0);
        }
        // q4: LDS
        {
            f16x8 a = *reinterpret_cast<const f16x8*>(ab + 4 * 32);
#pragma unroll
            for (int m = 0; m < 8; ++m) {
                f16x8 b = *reinterpret_cast<const f16x8*>(&blds[0][nIdx[m]][l]);
                C[m] = __builtin_amdgcn_mfma_f32_16x16x32_f16(a, b, C[m], 0, 0, 0);
            }
        }
        // stream q7 (consumed after 16 more MFMAs)
        f16x8 S7[8];
#pragma unroll
        for (int m = 0; m < 8; ++m)
            S7[m] = *reinterpret_cast<const f16x8*>(bfragsG + (nIdx[m] * 8 + 7) * 64 + l);
        // q5: LDS
        {
            f16x8 a = *reinterpret_cast<const f16x8*>(ab + 5 * 32);
#pragma unroll
            for (int m = 0; m < 8; ++m) {
                f16x8 b = *reinterpret_cast<const f16x8*>(&blds[1][nIdx[m]][l]);
                C[m] = __builtin_amdgcn_mfma_f32_16x16x32_f16(a, b, C[m], 0, 0, 0);
            }
        }
        // q6, q7: streamed
        {
            f16x8 a = *reinterpret_cast<const f16x8*>(ab + 6 * 32);
#pragma unroll
            for (int m = 0; m < 8; ++m)
                C[m] = __builtin_amdgcn_mfma_f32_16x16x32_f16(a, S6[m], C[m], 0, 0, 0);
        }
        {
            f16x8 a = *reinterpret_cast<const f16x8*>(ab + 7 * 32);
#pragma unroll
            for (int m = 0; m < 8; ++m)
                C[m] = __builtin_amdgcn_mfma_f32_16x16x32_f16(a, S7[m], C[m], 0, 0, 0);
        }

        // ---- epilogue (fully in-register): lane owns (jloc, samples 4sg+r) ----
        // C select by half WITHOUT runtime array indexing (cndmask, not scratch)
        f32x4 Cs[4];
#pragma unroll
        for (int g = 0; g < 4; ++g) Cs[g] = i_ ? C[g * 2 + 1] : C[g * 2];

        float hv[4];
#pragma unroll
        for (int r = 0; r < 4; ++r) {
            float pre[4];
#pragma unroll
            for (int g = 0; g < 4; ++g)
                pre[g] = fdot2(xwp0[g], xr[r].x,
                         fdot2(xwp1[g], xr[r].y, Cs[g][r] + bias_[g]));
            const float fg = sigmoidf_(pre[0]);
            const float ig = sigmoidf_(pre[1]);
            const float ug = tanhf_(pre[2]);
            const float og = sigmoidf_(pre[3]);
            cst[r] = fg * cst[r] + ig * ug;
            hv[r] = og * tanhf_(cst[r]);
            comb[cur ^ 1][4 * sg + r][jloc] = (_Float16)hv[r];
        }

        // head partials: reduce over j within wave (jj bits + half bit)
#pragma unroll
        for (int r = 0; r < 4; ++r) {
            float p = hv[r] * hwj;
            p += __shfl_xor(p, 1);
            p += __shfl_xor(p, 2);
            p += __shfl_xor(p, 4);
            p += __shfl_xor(p, 8);
            p += __shfl_xor(p, 32);
            if (jj == 0 && i_ == 0) redL[cur][w][sg][r] = p;
        }
        __syncthreads();                     // one barrier per step

        if (tid < 8) {
            float acc = hb;
#pragma unroll
            for (int ww = 0; ww < 8; ++ww) acc += redL[cur][ww][tid >> 2][tid & 3];
            out[(size_t)t * BATCH + sbase + tid] = acc;
        }
    }
}

extern "C" void kernel_launch(void* const* d_in, const int* in_sizes, int n_in,
                              void* d_out, int out_size, void* d_ws, size_t ws_size,
                              hipStream_t stream) {
    const float* inputs = (const float*)d_in[0];
    const float* fm_w = (const float*)d_in[1];  const float* fm_b = (const float*)d_in[2];
    const float* c1_w = (const float*)d_in[3];  const float* c1_b = (const float*)d_in[4];
    const float* p1_w = (const float*)d_in[5];  const float* p1_b = (const float*)d_in[6];
    const float* c2_w = (const float*)d_in[7];  const float* c2_b = (const float*)d_in[8];
    const float* p2_w = (const float*)d_in[9];  const float* p2_b = (const float*)d_in[10];
    const float* c3_w = (const float*)d_in[11]; const float* c3_b = (const float*)d_in[12];
    const float* f_w  = (const float*)d_in[13]; const float* f_b  = (const float*)d_in[14];
    const float* i_w  = (const float*)d_in[15]; const float* i_b  = (const float*)d_in[16];
    const float* u_w  = (const float*)d_in[17]; const float* u_b  = (const float*)d_in[18];
    const float* o_w  = (const float*)d_in[19]; const float* o_b  = (const float*)d_in[20];
    const float* head_w = (const float*)d_in[21];
    const float* head_b = (const float*)d_in[22];

    // workspace layout (16B aligned)
    uint4*     bfragsG = (uint4*)d_ws;                                // 524288 B
    _Float16*  xwG     = (_Float16*)((char*)d_ws + 524288);           //   8192 B
    _Float16*  feats   = (_Float16*)((char*)d_ws + 532480);           // 1048576 B
    float*     qw      = (float*)((char*)d_ws + 1581056);             //   3120 B

    hipLaunchKernelGGL(concat_qw, dim3(1), dim3(256), 0, stream,
                       fm_w, fm_b, c1_w, c1_b, p1_w, p1_b, c2_w, c2_b,
                       p2_w, p2_b, c3_w, c3_b, qw);
    hipLaunchKernelGGL(pack_bfrag, dim3(128), dim3(256), 0, stream,
                       f_w, i_w, u_w, o_w, bfragsG);
    hipLaunchKernelGGL(pack_xw, dim3(16), dim3(256), 0, stream,
                       f_w, i_w, u_w, o_w, xwG);
    hipLaunchKernelGGL(qcnn_kernel, dim3(512), dim3(256), 0, stream,
                       inputs, qw, feats);
    hipLaunchKernelGGL(lstm_kernel, dim3(64), dim3(512), 0, stream,
                       bfragsG, xwG, feats,
                       f_b, i_b, u_b, o_b, head_w, head_b, (float*)d_out);
}

// Round 10
// 636.657 us; speedup vs baseline: 2.3332x; 2.3332x over previous
//
#include <hip/hip_runtime.h>
#include <hip/hip_bf16.h>
#include <hip/hip_fp16.h>
#include <stdint.h>

#define T_STEPS 256
#define BATCH 512

typedef _Float16 f16x8 __attribute__((ext_vector_type(8)));
typedef _Float16 h2_t  __attribute__((ext_vector_type(2)));
typedef float    f32x4 __attribute__((ext_vector_type(4)));

__device__ __forceinline__ float fdot2(uint32_t w, uint32_t c, float acc) {
#if __has_builtin(__builtin_amdgcn_fdot2)
    h2_t a, b;
    __builtin_memcpy(&a, &w, 4);
    __builtin_memcpy(&b, &c, 4);
    return __builtin_amdgcn_fdot2(a, b, acc, false);
#else
    union { uint32_t u; _Float16 h[2]; } A, B;
    A.u = w; B.u = c;
    return acc + (float)A.h[0]*(float)B.h[0] + (float)A.h[1]*(float)B.h[1];
#endif
}

__device__ __forceinline__ float sigmoidf_(float x) {
    return 1.f / (1.f + __expf(-x));
}
__device__ __forceinline__ float tanhf_(float x) {
    float ax = fabsf(x);
    float e = __expf(-2.f * ax);
    float r = (1.f - e) / (1.f + e);
    return copysignf(r, x);
}

// pick-of-4 by d (0..3) without runtime array indexing (3 cndmask)
__device__ __forceinline__ float sel4(int d, float a, float b, float c, float e) {
    float lo = (d & 1) ? b : a;
    float hi = (d & 1) ? e : c;
    return (d & 2) ? hi : lo;
}

// resident-B MFMA: B pinned in AGPR via "a" constraint
#define MFMA_AG(c, aa, bb) \
    asm volatile("v_mfma_f32_16x16x32_f16 %0, %1, %2, %0" : "+v"(c) : "v"(aa), "a"(bb))

// ---------------- prep: concat QCNN weights ----------------
__global__ void concat_qw(const float* __restrict__ fm_w, const float* __restrict__ fm_b,
                          const float* __restrict__ c1_w, const float* __restrict__ c1_b,
                          const float* __restrict__ p1_w, const float* __restrict__ p1_b,
                          const float* __restrict__ c2_w, const float* __restrict__ c2_b,
                          const float* __restrict__ p2_w, const float* __restrict__ p2_b,
                          const float* __restrict__ c3_w, const float* __restrict__ c3_b,
                          float* __restrict__ qw) {
    for (int k = threadIdx.x; k < 780; k += 256) {
        float v;
        if      (k < 128) v = fm_w[k];
        else if (k < 144) v = fm_b[k-128];
        else if (k < 400) v = c1_w[k-144];
        else if (k < 416) v = c1_b[k-400];
        else if (k < 608) v = p1_w[k-416];
        else if (k < 620) v = p1_b[k-608];
        else if (k < 716) v = c2_w[k-620];
        else if (k < 724) v = c2_b[k-716];
        else if (k < 756) v = p2_w[k-724];
        else if (k < 760) v = p2_b[k-756];
        else if (k < 776) v = c3_w[k-760];
        else              v = c3_b[k-776];
        qw[k] = v;
    }
}

// ---------------- prep: B-fragments (f16) ----------------
// bfragsG[((n*8+q)*64+l)]: N-tile n (col = n*16 + (l&15) = gate*256 + j),
// K-tile q (k = q*32 + (l>>4)*8 + e). k-order errors cancel (A same mapping).
__global__ void pack_bfrag(const float* __restrict__ f_w, const float* __restrict__ i_w,
                           const float* __restrict__ u_w, const float* __restrict__ o_w,
                           uint4* __restrict__ bfragsG) {
    int idx = blockIdx.x * 256 + threadIdx.x;      // 0..32767
    int l = idx & 63, q = (idx >> 6) & 7, n = idx >> 9;
    int col = n * 16 + (l & 15);
    int g = col >> 8, j = col & 255;
    const float* W = (g == 0) ? f_w : (g == 1) ? i_w : (g == 2) ? u_w : o_w;
    union { uint4 u; _Float16 h[8]; } P;
#pragma unroll
    for (int e = 0; e < 8; ++e) {
        int k = q * 32 + ((l >> 4) * 8) + e;       // 0..255 (h part only)
        P.h[e] = (_Float16)W[j * 260 + 4 + k];
    }
    bfragsG[idx] = P.u;
}

// ---------------- prep: x-part weights xwG[g][k][j] f16 ----------------
__global__ void pack_xw(const float* __restrict__ f_w, const float* __restrict__ i_w,
                        const float* __restrict__ u_w, const float* __restrict__ o_w,
                        _Float16* __restrict__ xwG) {
    int t = blockIdx.x * 256 + threadIdx.x;        // 0..4095
    int g = t >> 10, k = (t >> 8) & 3, j = t & 255;
    const float* W = (g == 0) ? f_w : (g == 1) ? i_w : (g == 2) ? u_w : o_w;
    xwG[t] = (_Float16)W[j * 260 + k];
}

// ---------------- QCNN feature extractor ----------------
__global__ void qcnn_kernel(const float* __restrict__ in, const float* __restrict__ qw,
                            _Float16* __restrict__ feats) {
    int r = blockIdx.x * 256 + threadIdx.x;   // 0..131071
    const float* x = in + (size_t)r * 8;
    float v0[8];
#pragma unroll
    for (int i = 0; i < 8; ++i) v0[i] = x[i];
    float v1[16];
#pragma unroll
    for (int o = 0; o < 16; ++o) {
        float s = qw[128 + o];
#pragma unroll
        for (int i = 0; i < 8; ++i) s += qw[o*8 + i] * v0[i];
        v1[o] = tanhf_(s);
    }
    float v2[16];
#pragma unroll
    for (int o = 0; o < 16; ++o) {
        float s = qw[400 + o];
#pragma unroll
        for (int i = 0; i < 16; ++i) s += qw[144 + o*16 + i] * v1[i];
        v2[o] = tanhf_(s);
    }
    float v3[12];
#pragma unroll
    for (int o = 0; o < 12; ++o) {
        float s = qw[608 + o];
#pragma unroll
        for (int i = 0; i < 16; ++i) s += qw[416 + o*16 + i] * v2[i];
        v3[o] = tanhf_(s);
    }
    float v4[8];
#pragma unroll
    for (int o = 0; o < 8; ++o) {
        float s = qw[716 + o];
#pragma unroll
        for (int i = 0; i < 12; ++i) s += qw[620 + o*12 + i] * v3[i];
        v4[o] = tanhf_(s);
    }
    float v5[4];
#pragma unroll
    for (int o = 0; o < 4; ++o) {
        float s = qw[756 + o];
#pragma unroll
        for (int i = 0; i < 8; ++i) s += qw[724 + o*8 + i] * v4[i];
        v5[o] = tanhf_(s);
    }
    union { uint32_t u[2]; _Float16 h[4]; } P;
#pragma unroll
    for (int o = 0; o < 4; ++o) {
        float s = qw[776 + o];
#pragma unroll
        for (int i = 0; i < 4; ++i) s += qw[760 + o*4 + i] * v5[i];
        P.h[o] = (_Float16)tanhf_(s);
    }
    *reinterpret_cast<uint2*>(feats + (size_t)r * 4) = make_uint2(P.u[0], P.u[1]);
}

// ---------------- persistent MFMA LSTM: 256 blocks x 256 threads ----------------
// Register budget that CLOSES (r6/r7 overcommitted 532/620 > 512 -> silent
// remat, ~550 extra VALU/wave/step): resident = q0..3 all 16 tiles = 64 frags
// = 256 AGPR exactly; peak VGPR ~170 -> 426 <= 512 with slack. LDS: q4,q5 all
// tiles (128 KB) + q6 of gate-o tiles n48..63 (16 KB). Streamed from L2: q6
// (g=0..2) + q7 = 16 frags/wave/step, issued at gate-block top, consumed >=20
// MFMAs (~340 cy) later -> latency covered.
// In-lane epilogue (audit of r7's layout): A row r holds sample r&1 (comb read
// [l&1]); C row = (l>>4)*4 + reg -> sample = reg&1 in EVERY lane. So lane l
// holds both samples of col l&15 for all its tiles; lane handles j =
// (w*4 + (l>>4))*16 + (l&15), selecting C[d] by d=l>>4 via cndmask (sel4) --
// the old l<16 strip extraction + LDS round-trip is deleted entirely.
__global__ __launch_bounds__(256, 1)
void lstm_kernel(const uint4* __restrict__ bfragsG, const _Float16* __restrict__ xwG,
                 const _Float16* __restrict__ feats,
                 const float* __restrict__ f_b, const float* __restrict__ i_b,
                 const float* __restrict__ u_b, const float* __restrict__ o_b,
                 const float* __restrict__ head_w, const float* __restrict__ head_bp,
                 float* __restrict__ out) {
    __shared__ uint4     blds45[2][64][64];          // 131072 B : B q=4,5 all tiles
    __shared__ uint4     blds6o[16][64];             //  16384 B : B q=6, tiles 48..63
    __shared__ __align__(16) _Float16 comb[2][2][256]; //  2048 B : [buf][sample][k]
    __shared__ float     redL[2][4][2];              //     64 B : [buf][wave][sample]

    const int tid = threadIdx.x;
    const int w   = tid >> 6;          // wave 0..3
    const int l   = tid & 63;
    const int d_  = l >> 4;            // lane's d-slot (0..3)
    const int jl  = (w * 4 + d_) * 16 + (l & 15);   // lane's output dim j
    const int s0  = blockIdx.x * 2;

    // ---- init LDS ----
    for (int idx = tid; idx < 8192; idx += 256) {
        int n = idx >> 7, qq = (idx >> 6) & 1, ll = idx & 63;
        blds45[qq][n][ll] = bfragsG[(n * 8 + 4 + qq) * 64 + ll];
    }
    for (int idx = tid; idx < 1024; idx += 256) {
        int nn = idx >> 6, ll = idx & 63;
        blds6o[nn][ll] = bfragsG[((48 + nn) * 8 + 6) * 64 + ll];
    }
    reinterpret_cast<uint32_t*>(&comb[0][0][0])[tid] = 0u;   // h_0 = 0 (buf 0)

    // ---- resident B -> AGPR (exactly 256 regs), q = 0..3 x 16 tiles ----
    f16x8 Br[16][4];
#pragma unroll
    for (int m = 0; m < 16; ++m) {
        const int n = (m >> 2) * 16 + w * 4 + (m & 3);
#pragma unroll
        for (int q = 0; q < 4; ++q) {
            Br[m][q] = *reinterpret_cast<const f16x8*>(bfragsG + (n * 8 + q) * 64 + l);
            asm volatile("" : "+a"(Br[m][q]));
        }
    }

    // ---- per-lane epilogue constants (at jl) ----
    float bias_[4] = { f_b[jl], i_b[jl], u_b[jl], o_b[jl] };
    uint32_t xwp0[4], xwp1[4];
#pragma unroll
    for (int g = 0; g < 4; ++g) {
        union { uint32_t u; _Float16 h[2]; } P;
        P.h[0] = xwG[g*1024 +       jl]; P.h[1] = xwG[g*1024 + 256 + jl];
        xwp0[g] = P.u;
        P.h[0] = xwG[g*1024 + 512 + jl]; P.h[1] = xwG[g*1024 + 768 + jl];
        xwp1[g] = P.u;
    }
    const float hwj = head_w[jl];
    const float hb  = head_bp[0];
    uint2 xr0 = *reinterpret_cast<const uint2*>(feats + ((size_t)0 * BATCH + s0    ) * 4);
    uint2 xr1 = *reinterpret_cast<const uint2*>(feats + ((size_t)0 * BATCH + s0 + 1) * 4);

    __syncthreads();

    float cs0 = 0.f, cs1 = 0.f;        // c-state for (jl, sample 0/1)

#pragma unroll 1
    for (int t = 0; t < T_STEPS; ++t) {
        const int cur = t & 1;
        uint2 xn0 = xr0, xn1 = xr1;
        if (t + 1 < T_STEPS) {
            xn0 = *reinterpret_cast<const uint2*>(feats + ((size_t)(t+1) * BATCH + s0    ) * 4);
            xn1 = *reinterpret_cast<const uint2*>(feats + ((size_t)(t+1) * BATCH + s0 + 1) * 4);
        }

        // ---- A fragments (8 x ds_read_b128); row r = sample r&1 ----
        const _Float16* ab = &comb[cur][l & 1][(l >> 4) * 8];
        f16x8 A_[8];
#pragma unroll
        for (int q = 0; q < 8; ++q)
            A_[q] = *reinterpret_cast<const f16x8*>(ab + q * 32);

        float gv0[4], gv1[4];          // selected gate values (samples 0,1)

        // ---- 4 gate blocks, ascending q within each (r7 numeric order) ----
#pragma unroll
        for (int g = 0; g < 4; ++g) {
            // stream loads for this block (consumed at q6/q7, >=20 MFMAs later)
            f16x8 s6[4], s7[4];
#pragma unroll
            for (int d = 0; d < 4; ++d) {
                const int n = g * 16 + w * 4 + d;
                if (g < 3) s6[d] = *reinterpret_cast<const f16x8*>(bfragsG + (n * 8 + 6) * 64 + l);
                else       s6[d] = *reinterpret_cast<const f16x8*>(&blds6o[w * 4 + d][l]);
                s7[d] = *reinterpret_cast<const f16x8*>(bfragsG + (n * 8 + 7) * 64 + l);
            }
            // LDS q4,q5
            f16x8 b4[4], b5[4];
#pragma unroll
            for (int d = 0; d < 4; ++d) {
                const int n = g * 16 + w * 4 + d;
                b4[d] = *reinterpret_cast<const f16x8*>(&blds45[0][n][l]);
                b5[d] = *reinterpret_cast<const f16x8*>(&blds45[1][n][l]);
            }

            f32x4 c0 = {0.f,0.f,0.f,0.f}, c1 = {0.f,0.f,0.f,0.f};
            f32x4 c2 = {0.f,0.f,0.f,0.f}, c3 = {0.f,0.f,0.f,0.f};
            asm volatile("s_nop 0" : "+v"(c0), "+v"(c1), "+v"(c2), "+v"(c3));

            // q0..3: AGPR-resident (asm)
#pragma unroll
            for (int q = 0; q < 4; ++q) {
                MFMA_AG(c0, A_[q], Br[4*g+0][q]); MFMA_AG(c1, A_[q], Br[4*g+1][q]);
                MFMA_AG(c2, A_[q], Br[4*g+2][q]); MFMA_AG(c3, A_[q], Br[4*g+3][q]);
            }
            // q4..7: intrinsic (compiler-managed waits & hazards)
            c0 = __builtin_amdgcn_mfma_f32_16x16x32_f16(A_[4], b4[0], c0, 0, 0, 0);
            c1 = __builtin_amdgcn_mfma_f32_16x16x32_f16(A_[4], b4[1], c1, 0, 0, 0);
            c2 = __builtin_amdgcn_mfma_f32_16x16x32_f16(A_[4], b4[2], c2, 0, 0, 0);
            c3 = __builtin_amdgcn_mfma_f32_16x16x32_f16(A_[4], b4[3], c3, 0, 0, 0);
            c0 = __builtin_amdgcn_mfma_f32_16x16x32_f16(A_[5], b5[0], c0, 0, 0, 0);
            c1 = __builtin_amdgcn_mfma_f32_16x16x32_f16(A_[5], b5[1], c1, 0, 0, 0);
            c2 = __builtin_amdgcn_mfma_f32_16x16x32_f16(A_[5], b5[2], c2, 0, 0, 0);
            c3 = __builtin_amdgcn_mfma_f32_16x16x32_f16(A_[5], b5[3], c3, 0, 0, 0);
            c0 = __builtin_amdgcn_mfma_f32_16x16x32_f16(A_[6], s6[0], c0, 0, 0, 0);
            c1 = __builtin_amdgcn_mfma_f32_16x16x32_f16(A_[6], s6[1], c1, 0, 0, 0);
            c2 = __builtin_amdgcn_mfma_f32_16x16x32_f16(A_[6], s6[2], c2, 0, 0, 0);
            c3 = __builtin_amdgcn_mfma_f32_16x16x32_f16(A_[6], s6[3], c3, 0, 0, 0);
            c0 = __builtin_amdgcn_mfma_f32_16x16x32_f16(A_[7], s7[0], c0, 0, 0, 0);
            c1 = __builtin_amdgcn_mfma_f32_16x16x32_f16(A_[7], s7[1], c1, 0, 0, 0);
            c2 = __builtin_amdgcn_mfma_f32_16x16x32_f16(A_[7], s7[2], c2, 0, 0, 0);
            c3 = __builtin_amdgcn_mfma_f32_16x16x32_f16(A_[7], s7[3], c3, 0, 0, 0);

            // in-lane select: lane's d-slot picks its tile; regs 0/1 = samples 0/1
            gv0[g] = sel4(d_, c0[0], c1[0], c2[0], c3[0]);
            gv1[g] = sel4(d_, c0[1], c1[1], c2[1], c3[1]);
        }

        // ---- epilogue: all in-register, lane owns (jl, s=0) and (jl, s=1) ----
        float pre0[4], pre1[4];
#pragma unroll
        for (int g = 0; g < 4; ++g) {
            pre0[g] = fdot2(xwp0[g], xr0.x, fdot2(xwp1[g], xr0.y, gv0[g] + bias_[g]));
            pre1[g] = fdot2(xwp0[g], xr1.x, fdot2(xwp1[g], xr1.y, gv1[g] + bias_[g]));
        }
        const float fg0 = sigmoidf_(pre0[0]), fg1 = sigmoidf_(pre1[0]);
        const float ig0 = sigmoidf_(pre0[1]), ig1 = sigmoidf_(pre1[1]);
        const float ug0 = tanhf_(pre0[2]),    ug1 = tanhf_(pre1[2]);
        const float og0 = sigmoidf_(pre0[3]), og1 = sigmoidf_(pre1[3]);
        cs0 = fg0 * cs0 + ig0 * ug0;
        cs1 = fg1 * cs1 + ig1 * ug1;
        const float h0 = og0 * tanhf_(cs0);
        const float h1 = og1 * tanhf_(cs1);

        comb[cur ^ 1][0][jl] = (_Float16)h0;
        comb[cur ^ 1][1][jl] = (_Float16)h1;

        // head partials: full-wave reduce (64 distinct j per wave)
        float p0 = h0 * hwj, p1 = h1 * hwj;
#pragma unroll
        for (int off = 32; off; off >>= 1) {
            p0 += __shfl_xor(p0, off);
            p1 += __shfl_xor(p1, off);
        }
        if (l == 0) { redL[cur][w][0] = p0; redL[cur][w][1] = p1; }

        xr0 = xn0; xr1 = xn1;
        __syncthreads();                       // one barrier per step

        if (tid < 2)
            out[(size_t)t * BATCH + s0 + tid] =
                (redL[cur][0][tid] + redL[cur][1][tid]) +
                (redL[cur][2][tid] + redL[cur][3][tid]) + hb;
    }
}

extern "C" void kernel_launch(void* const* d_in, const int* in_sizes, int n_in,
                              void* d_out, int out_size, void* d_ws, size_t ws_size,
                              hipStream_t stream) {
    const float* inputs = (const float*)d_in[0];
    const float* fm_w = (const float*)d_in[1];  const float* fm_b = (const float*)d_in[2];
    const float* c1_w = (const float*)d_in[3];  const float* c1_b = (const float*)d_in[4];
    const float* p1_w = (const float*)d_in[5];  const float* p1_b = (const float*)d_in[6];
    const float* c2_w = (const float*)d_in[7];  const float* c2_b = (const float*)d_in[8];
    const float* p2_w = (const float*)d_in[9];  const float* p2_b = (const float*)d_in[10];
    const float* c3_w = (const float*)d_in[11]; const float* c3_b = (const float*)d_in[12];
    const float* f_w  = (const float*)d_in[13]; const float* f_b  = (const float*)d_in[14];
    const float* i_w  = (const float*)d_in[15]; const float* i_b  = (const float*)d_in[16];
    const float* u_w  = (const float*)d_in[17]; const float* u_b  = (const float*)d_in[18];
    const float* o_w  = (const float*)d_in[19]; const float* o_b  = (const float*)d_in[20];
    const float* head_w = (const float*)d_in[21];
    const float* head_b = (const float*)d_in[22];

    // workspace layout (16B aligned)
    uint4*     bfragsG = (uint4*)d_ws;                                // 524288 B
    _Float16*  xwG     = (_Float16*)((char*)d_ws + 524288);           //   8192 B
    _Float16*  feats   = (_Float16*)((char*)d_ws + 532480);           // 1048576 B
    float*     qw      = (float*)((char*)d_ws + 1581056);             //   3120 B

    hipLaunchKernelGGL(concat_qw, dim3(1), dim3(256), 0, stream,
                       fm_w, fm_b, c1_w, c1_b, p1_w, p1_b, c2_w, c2_b,
                       p2_w, p2_b, c3_w, c3_b, qw);
    hipLaunchKernelGGL(pack_bfrag, dim3(128), dim3(256), 0, stream,
                       f_w, i_w, u_w, o_w, bfragsG);
    hipLaunchKernelGGL(pack_xw, dim3(16), dim3(256), 0, stream,
                       f_w, i_w, u_w, o_w, xwG);
    hipLaunchKernelGGL(qcnn_kernel, dim3(512), dim3(256), 0, stream,
                       inputs, qw, feats);
    hipLaunchKernelGGL(lstm_kernel, dim3(256), dim3(256), 0, stream,
                       bfragsG, xwG, feats,
                       f_b, i_b, u_b, o_b, head_w, head_b, (float*)d_out);
}